// Round 7
// baseline (202.138 us; speedup 1.0000x reference)
//
#include <hip/hip_runtime.h>

typedef __attribute__((ext_vector_type(8))) short short8;
typedef __attribute__((ext_vector_type(4))) short short4v;
typedef __attribute__((ext_vector_type(4))) float floatx4;
typedef __attribute__((ext_vector_type(2))) unsigned int uint2v;

#define S_LEN 2048
#define NH 12
#define HD 64
#define EMB 768
#define E3 2304

__device__ __forceinline__ unsigned short f2bf(float f) {
    unsigned int u = __builtin_bit_cast(unsigned int, f);
    u += 0x7FFFu + ((u >> 16) & 1u);   // RNE
    return (unsigned short)(u >> 16);
}

__device__ __forceinline__ unsigned int pack2bf(float a, float b) {
#if __has_builtin(__builtin_amdgcn_cvt_pk_bf16_f32)
    typedef __attribute__((ext_vector_type(2))) short short2v;
    short2v r = __builtin_amdgcn_cvt_pk_bf16_f32(a, b);
    return __builtin_bit_cast(unsigned int, r);
#else
    return (unsigned int)f2bf(a) | ((unsigned int)f2bf(b) << 16);
#endif
}

// async global->LDS, 16B/lane; LDS dest = wave-uniform base + lane*16
__device__ __forceinline__ void gl_lds16(const void* g, void* l) {
    __builtin_amdgcn_global_load_lds(
        (const __attribute__((address_space(1))) unsigned int*)g,
        (__attribute__((address_space(3))) unsigned int*)l, 16, 0, 0);
}

// ------------- fused input conversion: x->bf16, W->Wt bf16 -------------------
__global__ __launch_bounds__(256) void conv_fused(const float* __restrict__ x,
                                                  ushort* __restrict__ xb,
                                                  const float* __restrict__ W,
                                                  ushort* __restrict__ Wt) {
    int tid = threadIdx.x;
    if (blockIdx.x < 6144) {                      // x: 8192*768 / 4 per thread
        int i = (blockIdx.x * 256 + tid) * 4;
        float4 f = *(const float4*)(x + i);
        ushort4 o;
        o.x = f2bf(f.x); o.y = f2bf(f.y); o.z = f2bf(f.z); o.w = f2bf(f.w);
        *(ushort4*)(xb + i) = o;
    } else {                                      // W transpose: 72 x 24 tiles of 32x32
        __shared__ float tile[32][33];
        int b2 = blockIdx.x - 6144;
        int n0 = (b2 % 72) * 32, k0 = (b2 / 72) * 32;
        int tx = tid & 31, ty = tid >> 5;
        for (int i = 0; i < 4; i++)
            tile[ty + i * 8][tx] = W[(size_t)(k0 + ty + i * 8) * E3 + n0 + tx];
        __syncthreads();
        for (int i = 0; i < 4; i++)
            Wt[(size_t)(n0 + ty + i * 8) * EMB + k0 + tx] = f2bf(tile[tx][ty + i * 8]);
    }
}

// ---------------- QKV GEMM: [8192,768] x [768,2304] + bias ----------------
// 128x128 tile, BK=64 (12 iters), gl_lds XOR-swizzled staging, hoisted
// addressing, LDS-transpose coalesced epilogue. (unchanged from r6)
__global__ __launch_bounds__(256) void qkv_gemm(const ushort* __restrict__ Xb,
                                                const ushort* __restrict__ Wt,
                                                const float* __restrict__ bias,
                                                ushort* __restrict__ QKb,
                                                ushort* __restrict__ Vt) {
    __shared__ ushort lds[16896];                 // 33792 B
    char* ldsb = (char*)lds;
    int tid  = threadIdx.x;
    int wv = tid >> 6, lane = tid & 63;
    int l15 = lane & 15, quad = lane >> 4;
    int r8 = lane >> 3, cc = lane & 7;
    int wm = wv >> 1, wn = wv & 1;
    int m0 = blockIdx.x * 128, n0 = blockIdx.y * 128;

    floatx4 acc[4][4] = {};

    const char* ag = (const char*)(Xb + (size_t)m0 * EMB)
                   + (wv * 32 + r8) * 1536 + (cc ^ r8) * 16;
    const char* bgp = (const char*)(Wt + (size_t)n0 * EMB)
                   + (wv * 32 + r8) * 1536 + (cc ^ r8) * 16;
    int ast = (wv * 32) * 128;
    int bst = 16384 + (wv * 32) * 128;
    int afo[2], bfo[2];
    for (int ch = 0; ch < 2; ch++) {
        int sw = ((ch * 4 + quad) ^ (l15 & 7)) * 16;
        afo[ch] = wm * 8192 + l15 * 128 + sw;
        bfo[ch] = 16384 + wn * 8192 + l15 * 128 + sw;
    }

    for (int k0 = 0; k0 < 12; k0++) {
        __syncthreads();
        for (int i = 0; i < 4; i++) {
            gl_lds16(ag + i * 12288, ldsb + ast + i * 1024);
            gl_lds16(bgp + i * 12288, ldsb + bst + i * 1024);
        }
        ag += 128;  bgp += 128;
        __syncthreads();
        for (int ch = 0; ch < 2; ch++) {
            short8 af[4], bf[4];
            for (int mi = 0; mi < 4; mi++)
                af[mi] = *(const short8*)(ldsb + afo[ch] + mi * 2048);
            for (int ni = 0; ni < 4; ni++)
                bf[ni] = *(const short8*)(ldsb + bfo[ch] + ni * 2048);
            for (int mi = 0; mi < 4; mi++)
                for (int ni = 0; ni < 4; ni++)
                    acc[mi][ni] = __builtin_amdgcn_mfma_f32_16x16x32_bf16(
                        af[mi], bf[ni], acc[mi][ni], 0, 0, 0);
        }
    }

    __syncthreads();
    int seg = n0 / EMB;
    if (seg < 2) {
        float scale = (seg == 0) ? 0.125f : 1.0f;
        for (int ni = 0; ni < 4; ni++) {
            int nl = wn * 64 + ni * 16 + l15;
            float bv = bias[n0 + nl];
            for (int mi = 0; mi < 4; mi++)
                for (int r = 0; r < 4; r++) {
                    int ml = wm * 64 + mi * 16 + quad * 4 + r;
                    lds[ml * 132 + nl] = f2bf((acc[mi][ni][r] + bv) * scale);
                }
        }
        __syncthreads();
        int row = tid >> 1, half2 = tid & 1;
        size_t gm = (size_t)(m0 + row);
        for (int i = 0; i < 8; i++) {
            uint4 v = *(const uint4*)&lds[row * 132 + half2 * 64 + i * 8];
            *(uint4*)&QKb[gm * 1536 + n0 + half2 * 64 + i * 8] = v;
        }
    } else {
        for (int ni = 0; ni < 4; ni++) {
            int nl = wn * 64 + ni * 16 + l15;
            float bv = bias[n0 + nl];
            for (int mi = 0; mi < 4; mi++) {
                int ml = wm * 64 + mi * 16 + quad * 4;
                ushort4 p4;
                p4.x = f2bf(acc[mi][ni][0] + bv);
                p4.y = f2bf(acc[mi][ni][1] + bv);
                p4.z = f2bf(acc[mi][ni][2] + bv);
                p4.w = f2bf(acc[mi][ni][3] + bv);
                *(ushort4*)&lds[nl * 132 + ml] = p4;
            }
        }
        __syncthreads();
        int row = tid >> 1, half2 = tid & 1;
        int nn = n0 + row - 1536;
        int hh = nn >> 6, d = nn & 63;
        int bb = m0 >> 11, s0 = m0 & 2047;
        for (int i = 0; i < 8; i++) {
            uint4 v = *(const uint4*)&lds[row * 132 + half2 * 64 + i * 8];
            *(uint4*)&Vt[((size_t)(bb * NH + hh) * HD + d) * S_LEN + s0 + half2 * 64 + i * 8] = v;
        }
    }
}

// ---------------- Attention: ReLU(Q K^T, causal) @ V  (Q pre-scaled) --------
// Wave-autonomous: block = 2 waves; each wave owns one (bh, 64-q-tile) item and
// a private 32KB LDS half (double-buffered 64-k stages). NO __syncthreads —
// staging synced by wave-local s_waitcnt vmcnt(16)/(0) inline asm, so prefetch
// stays in flight across stage boundaries (never drains to 0 mid-item).
__global__ __launch_bounds__(128) void attn(const ushort* __restrict__ QKb,
                                            const ushort* __restrict__ Vt,
                                            float* __restrict__ out) {
    __shared__ ushort lds[32768];   // 64KB; wave w owns [w*32768, +32768) bytes
    char* ldsb = (char*)lds;
    int tid = threadIdx.x;
    int w = tid >> 6, lane = tid & 63;
    int l15 = lane & 15, quad = lane >> 4;
    int r8 = lane >> 3, cc = lane & 7;
    int qh = quad >> 1, qlo = quad & 1;

    // schedule: block g pairs qt=31-g (wave0) with qt=15-g (wave1), same bh.
    // wave1's K/V range is a subset of wave0's -> L2 locality; heavy blocks first.
    int g = blockIdx.x / 48, bh = blockIdx.x % 48;
    int qt = w ? (15 - g) : (31 - g);
    int bg = bh / NH, h = bh % NH;

    const char* Kb = (const char*)(QKb + (size_t)bg * S_LEN * 1536 + 768 + h * 64)
                   + r8 * 3072 + (cc ^ r8) * 16;          // K row stride 3072 B
    const char* Vb = (const char*)(Vt + (size_t)bh * HD * S_LEN)
                   + r8 * 4096 + (cc ^ r8) * 16;          // V row stride 4096 B
    const ushort* Qcol = QKb + (size_t)bg * S_LEN * 1536 + h * 64;

    int wb = w * 32768;
    // hoisted LDS read offsets (+ p*16384 per buffer)
    int kfo[2];
    for (int ch = 0; ch < 2; ch++)
        kfo[ch] = wb + l15 * 128 + (((ch * 4 + quad) ^ (l15 & 7)) * 16);
    int vfo[4];
    for (int kb = 0; kb < 4; kb++)
        vfo[kb] = wb + 8192 + l15 * 128 + (((kb * 2 + qh) ^ (l15 & 7)) * 16) + qlo * 8;

    // stage 0 into buffer 0 (16 gl_lds: K 8KB rows of 128B, V 8KB rows of 128B)
    for (int i = 0; i < 8; i++)
        gl_lds16(Kb + i * 24576, ldsb + wb + i * 1024);
    for (int i = 0; i < 8; i++)
        gl_lds16(Vb + i * 32768, ldsb + wb + 8192 + i * 1024);

    // Q fragments (B-operand layout), 8 x b128 global loads
    short8 qf[4][2];
    for (int nq = 0; nq < 4; nq++)
        for (int ch = 0; ch < 2; ch++)
            qf[nq][ch] = *(const short8*)(Qcol +
                (size_t)(qt * 64 + nq * 16 + l15) * 1536 + ch * 32 + quad * 8);

    floatx4 acco[4][4] = {};
    int p = 0;
    for (int st = 0; st <= qt; st++) {
        if (st < qt) {      // prefetch stage st+1 into buf p^1, then wait for buf p
            const char* ks = Kb + (size_t)(st + 1) * 196608;
            const char* vs = Vb + (st + 1) * 128;
            int d = wb + (p ^ 1) * 16384;
            for (int i = 0; i < 8; i++)
                gl_lds16(ks + i * 24576, ldsb + d + i * 1024);
            for (int i = 0; i < 8; i++)
                gl_lds16(vs + i * 32768, ldsb + d + 8192 + i * 1024);
            asm volatile("s_waitcnt vmcnt(16)" ::: "memory");
        } else {
            asm volatile("s_waitcnt vmcnt(0)" ::: "memory");
        }
        int pb = p * 16384;
        bool diag = (st == qt);

        short4v vf[4][4];
        for (int kb = 0; kb < 4; kb++)
            for (int ni = 0; ni < 4; ni++)
                vf[kb][ni] = *(const short4v*)(ldsb + pb + vfo[kb] + ni * 2048);
        short8 kf[4][2];
        for (int mk = 0; mk < 4; mk++)
            for (int ch = 0; ch < 2; ch++)
                kf[mk][ch] = *(const short8*)(ldsb + pb + kfo[ch] + mk * 2048);

        for (int nq = 0; nq < 4; nq++) {
            // S^T = K·Q^T : 64 k-rows x 16 q, K(d)=64
            floatx4 stc[4] = {};
            for (int ch = 0; ch < 2; ch++)
                for (int mk = 0; mk < 4; mk++)
                    stc[mk] = __builtin_amdgcn_mfma_f32_16x16x32_bf16(
                        kf[mk][ch], qf[nq][ch], stc[mk], 0, 0, 0);
            // ReLU + causal mask + pack (PV A-frag layout)
            unsigned int pk[4][2];
            for (int mk = 0; mk < 4; mk++) {
                float e[4];
                for (int r = 0; r < 4; r++) e[r] = fmaxf(stc[mk][r], 0.0f);
                if (diag) {
                    int kl = mk * 16 + quad * 4;
                    int ql = nq * 16 + l15;
                    for (int r = 0; r < 4; r++)
                        if (kl + r > ql) e[r] = 0.0f;
                }
                pk[mk][0] = pack2bf(e[0], e[1]);
                pk[mk][1] = pack2bf(e[2], e[3]);
            }
            // O += P·V via 16x16x16 (A in-register, B = V from LDS)
            for (int mk = 0; mk < 4; mk++) {
                short4v a = __builtin_bit_cast(short4v, (uint2v){pk[mk][0], pk[mk][1]});
                for (int ni = 0; ni < 4; ni++)
                    acco[nq][ni] = __builtin_amdgcn_mfma_f32_16x16x16bf16_1k(
                        a, vf[mk][ni], acco[nq][ni], 0, 0, 0);
            }
        }
        p ^= 1;
    }

    // epilogue: out[b][s][h*64+d] fp32
    for (int nq = 0; nq < 4; nq++) {
        for (int ni = 0; ni < 4; ni++) {
            int d = ni * 16 + l15;
            for (int r = 0; r < 4; r++) {
                int s = qt * 64 + nq * 16 + quad * 4 + r;
                out[((size_t)bg * S_LEN + s) * EMB + h * 64 + d] = acco[nq][ni][r];
            }
        }
    }
}

extern "C" void kernel_launch(void* const* d_in, const int* in_sizes, int n_in,
                              void* d_out, int out_size, void* d_ws, size_t ws_size,
                              hipStream_t stream) {
    const float* x    = (const float*)d_in[0];   // [4,2048,768]
    const float* W    = (const float*)d_in[1];   // [768,2304]
    const float* bias = (const float*)d_in[2];   // [2304]
    float* out = (float*)d_out;                  // [4,2048,768] fp32

    char* ws = (char*)d_ws;
    const size_t SZ_X  = (size_t)8192 * EMB * 2;
    const size_t SZ_W  = (size_t)E3 * EMB * 2;
    const size_t SZ_QK = (size_t)8192 * 1536 * 2;
    ushort* Xb  = (ushort*)(ws);
    ushort* Wt  = (ushort*)(ws + SZ_X);
    ushort* QKb = (ushort*)(ws + SZ_X + SZ_W);
    ushort* Vt  = (ushort*)(ws + SZ_X + SZ_W + SZ_QK);

    conv_fused<<<dim3(6144 + 1728), dim3(256), 0, stream>>>(x, Xb, W, Wt);
    qkv_gemm<<<dim3(64, 18), dim3(256), 0, stream>>>(Xb, Wt, bias, QKb, Vt);
    attn<<<dim3(768), dim3(128), 0, stream>>>(QKb, Vt, out);
}